// Round 1
// baseline (109.314 us; speedup 1.0000x reference)
//
#include <hip/hip_runtime.h>

#define SN 128
#define SPK 512

constexpr float GMIN  = 0.1f;
constexpr float PFRAC = 0.3f;
constexpr float GMAX  = 1.0f;

// Layout: block = (s, p, xc): covers plane p of sample s, x in [xc*32, xc*32+32).
// Thread t: Xl = t>>4 (x-pair within chunk), yc = t&15 (8-wide y chunk).
// Registers v[0..7]  = (x_even,   y = yc*8 + j)
//           v[8..15] = (x_even+1, y = yc*8 + j)
// Pooled output per thread: 4 consecutive Y cells -> one float4 store.

__global__ __launch_bounds__(256, 4) void trace_kernel(
    const int*   __restrict__ event,   // (SN, SPK, 3) int32: x, y, pol
    const float* __restrict__ ts,      // (SN, SPK) f32, ascending
    const int*   __restrict__ tt,      // (SN, SPK) int32 in [0,8)
    const int*   __restrict__ length,  // (SN,) int32
    float*       __restrict__ out)     // (SN, 8, 2, 64, 64) f32
{
    __shared__ uint2 sched[SPK + 1];   // .x = bits(m), .y = meta
    __shared__ int   ttbuf[SPK];
    __shared__ int   nlast[8];

    const int wg = blockIdx.x;
    const int s  = wg >> 3;
    const int p  = (wg >> 2) & 1;
    const int xc = wg & 3;
    const int t  = threadIdx.x;

    const int len = length[s];

    // ---- build per-sample schedule in LDS ----
    // meta: bits 0-14 = packed pos (p<<14 | x<<7 | y), bit 15 = length-gate,
    //       bits 16-19 = snapshot slot + 1 (0 = none, filled below)
    for (int n = t; n < SPK; n += 256) {
        int tval = tt[s * SPK + n];
        ttbuf[n] = tval;
        float m = 1.0f;
        unsigned meta = 0u;
        if (n >= 1) {
            float ta = ts[s * SPK + n - 1];
            float tb = ts[s * SPK + n];
            m = expf((ta - tb) * 0.01f);          // exp(dt/TAU), TAU=100
            const int* ev = event + (s * SPK + n) * 3;
            int xs = ev[0], ys = ev[1], ps = ev[2];
            meta = (unsigned)((ps << 14) | (xs << 7) | ys);
            if (len > n) meta |= (1u << 15);
        }
        sched[n] = make_uint2(__float_as_uint(m), meta);
    }
    if (t == 0) sched[SPK] = make_uint2(0u, 0u);  // prefetch pad (meta=0: no owner-add, no snap)
    __syncthreads();

    // mark last occurrence of each slot value (the surviving snapshot)
    if (t < 8) {
        int found = -1;
        for (int n = SPK - 1; n >= 1; --n) {
            if (ttbuf[n] == t) { found = n; break; }
        }
        nlast[t] = found;
        if (found >= 0) sched[found].y |= (unsigned)(t + 1) << 16;
    }
    __syncthreads();

    const int Xl     = t >> 4;
    const int yc     = t & 15;
    const int x_even = xc * 32 + 2 * Xl;
    // owner pattern: pos with x-LSB (bit 7) and y low-3 (bits 0-2) stripped
    const unsigned mypat = (unsigned)((p << 14) | (x_even << 7) | (yc << 3));

    float v[16];
#pragma unroll
    for (int j = 0; j < 16; ++j) v[j] = 0.0f;

    // initial condition: +0.27 at (p0, x0, y0) of slot-0 state
    bool own0 = false; int j0 = 0;
    {
        const int* ev0 = event + s * SPK * 3;
        int x0 = ev0[0], y0 = ev0[1], p0 = ev0[2];
        unsigned pos0 = (unsigned)((p0 << 14) | (x0 << 7) | y0);
        if ((pos0 & 0x7F78u) == mypat) {
            own0 = true;
            j0 = ((x0 & 1) << 3) | (y0 & 7);
#pragma unroll
            for (int j = 0; j < 16; ++j) if (j == j0) v[j] = PFRAC * (GMAX - GMIN);
        }
    }

    // ---- main sequential loop: no inter-thread communication ----
    uint2 sc = sched[1];
    for (int n = 1; n < SPK; ++n) {
        uint2 nx = sched[n + 1];                 // prefetch next step's schedule
        float    m    = __uint_as_float(sc.x);
        unsigned meta = sc.y;

#pragma unroll
        for (int j = 0; j < 16; ++j) v[j] = fmaf(m, v[j] - GMIN, GMIN);

        if ((meta & 0x7F78u) == mypat) {         // this thread owns the spike cell
            float ag = (meta & (1u << 15)) ? PFRAC : 0.0f;
            int jidx = (int)(((meta >> 7) & 1u) << 3) | (int)(meta & 7u);
#pragma unroll
            for (int j = 0; j < 16; ++j)
                if (j == jidx) v[j] = fmaf(ag, GMAX - v[j], v[j]);
        }

        unsigned snap = meta >> 16;
        if (snap) {                              // block-uniform branch
            int r = (int)snap - 1;
            float4 o;
            o.x = fmaxf(fmaxf(v[0], v[1]), fmaxf(v[8],  v[9]));
            o.y = fmaxf(fmaxf(v[2], v[3]), fmaxf(v[10], v[11]));
            o.z = fmaxf(fmaxf(v[4], v[5]), fmaxf(v[12], v[13]));
            o.w = fmaxf(fmaxf(v[6], v[7]), fmaxf(v[14], v[15]));
            int X = xc * 16 + Xl;
            float* dst = out + (size_t)((((s * 8 + r) * 2 + p) * 64 + X) * 64 + yc * 4);
            *reinterpret_cast<float4*>(dst) = o;
        }
        sc = nx;
    }

    // ---- slots never written at n>=1: default snapshots ----
    for (int r = 0; r < 8; ++r) {
        if (nlast[r] < 0) {
            float4 o = make_float4(0.f, 0.f, 0.f, 0.f);
            if (r == 0 && own0) {                // slot 0 keeps the single init point
                float val = PFRAC * (GMAX - GMIN);
                int k0 = (j0 & 7) >> 1;
                if      (k0 == 0) o.x = val;
                else if (k0 == 1) o.y = val;
                else if (k0 == 2) o.z = val;
                else              o.w = val;
            }
            int X = xc * 16 + Xl;
            float* dst = out + (size_t)((((s * 8 + r) * 2 + p) * 64 + X) * 64 + yc * 4);
            *reinterpret_cast<float4*>(dst) = o;
        }
    }
}

extern "C" void kernel_launch(void* const* d_in, const int* in_sizes, int n_in,
                              void* d_out, int out_size, void* d_ws, size_t ws_size,
                              hipStream_t stream) {
    const int*   event  = (const int*)  d_in[0];
    const float* ts     = (const float*)d_in[1];
    const int*   tt     = (const int*)  d_in[2];
    const int*   length = (const int*)  d_in[3];
    float*       out    = (float*)d_out;

    // 128 samples x 2 polarities x 4 x-chunks
    trace_kernel<<<dim3(SN * 2 * 4), dim3(256), 0, stream>>>(event, ts, tt, length, out);
}

// Round 2
// 85.671 us; speedup vs baseline: 1.2760x; 1.2760x over previous
//
#include <hip/hip_runtime.h>

#define SN 128
#define SPK 512

constexpr float GMIN  = 0.1f;
constexpr float PFRAC = 0.3f;
constexpr float GMAX  = 1.0f;

// Layout: block = (s, p, xc): plane p of sample s, x in [xc*32, xc*32+32).
// Thread t: Xl = t>>4 (x-pair within chunk), yc = t&15 (8-wide y chunk).
// v[0..7]  = (x_even,   y = yc*8 + j)
// v[8..15] = (x_even+1, y = yc*8 + j)
// Per step: v = m*(v-GMIN)+GMIN  ==  fma(m, v, b) with b = GMIN*(1-m).
// Schedule entry (uint4): x=bits(m), y=bits(b), z=meta, w=0
// meta: bits 0-14 pos (p<<14|x<<7|y), bit 15 len-gate, bits 16-19 snap-slot+1,
//       bits 20-22 tt value.

__global__ __launch_bounds__(256, 4) void trace_kernel(
    const int*   __restrict__ event,   // (SN, SPK, 3) int32: x, y, pol
    const float* __restrict__ ts,      // (SN, SPK) f32, ascending
    const int*   __restrict__ tt,      // (SN, SPK) int32 in [0,8)
    const int*   __restrict__ length,  // (SN,) int32
    float*       __restrict__ out)     // (SN, 8, 2, 64, 64) f32
{
    __shared__ uint4 sched[SPK + 3];   // +3 pad entries (identity steps)
    __shared__ int   nlast[8];

    const int wg = blockIdx.x;
    const int s  = wg >> 3;
    const int p  = (wg >> 2) & 1;
    const int xc = wg & 3;
    const int t  = threadIdx.x;

    const int len = length[s];

    // ---- build per-sample schedule in LDS ----
    for (int n = t; n < SPK + 3; n += 256) {
        float m = 1.0f, b = 0.0f;
        unsigned meta = 0u;
        if (n < SPK) {
            int tval = tt[s * SPK + n];
            meta = (unsigned)tval << 20;
            if (n >= 1) {
                float dt = ts[s * SPK + n - 1] - ts[s * SPK + n];
                m = expf(dt * 0.01f);            // exp(dt/TAU), TAU=100
                b = GMIN * (1.0f - m);
                const int* ev = event + (s * SPK + n) * 3;
                meta |= (unsigned)((ev[2] << 14) | (ev[0] << 7) | ev[1]);
                if (len > n) meta |= (1u << 15);
            }
        }
        sched[n] = make_uint4(__float_as_uint(m), __float_as_uint(b), meta, 0u);
    }
    __syncthreads();

    // mark last occurrence of each slot value (the surviving snapshot)
    if (t < 8) {
        int found = -1;
        for (int n = SPK - 1; n >= 1; --n) {
            if ((int)((sched[n].z >> 20) & 7u) == t) { found = n; break; }
        }
        nlast[t] = found;
        if (found >= 0) sched[found].z |= (unsigned)(t + 1) << 16;
    }
    __syncthreads();

    const int Xl     = t >> 4;
    const int yc     = t & 15;
    const int x_even = xc * 32 + 2 * Xl;
    const unsigned mypat = (unsigned)((p << 14) | (x_even << 7) | (yc << 3));
    const int X = xc * 16 + Xl;

    float v[16];
#pragma unroll
    for (int j = 0; j < 16; ++j) v[j] = 0.0f;

    // initial condition: +PFRAC*(GMAX-GMIN) at (p0, x0, y0) of slot-0 state
    bool own0 = false; int j0 = 0;
    {
        const int* ev0 = event + s * SPK * 3;
        int x0 = ev0[0], y0 = ev0[1], p0 = ev0[2];
        unsigned pos0 = (unsigned)((p0 << 14) | (x0 << 7) | y0);
        if ((pos0 & 0x7F78u) == mypat) {
            own0 = true;
            j0 = ((x0 & 1) << 3) | (y0 & 7);
#pragma unroll
            for (int j = 0; j < 16; ++j) if (j == j0) v[j] = PFRAC * (GMAX - GMIN);
        }
    }

#define STEP(c)                                                               \
    {                                                                         \
        float    m_   = __uint_as_float((c).x);                               \
        float    b_   = __uint_as_float((c).y);                               \
        unsigned meta = (c).z;                                                \
        _Pragma("unroll")                                                     \
        for (int j = 0; j < 16; ++j) v[j] = fmaf(m_, v[j], b_);               \
        if ((meta & 0x7F78u) == mypat) {                                      \
            float ag  = (meta & (1u << 15)) ? PFRAC : 0.0f;                   \
            int  jidx = (int)(((meta >> 7) & 1u) << 3) | (int)(meta & 7u);    \
            _Pragma("unroll")                                                 \
            for (int j = 0; j < 16; ++j)                                      \
                if (j == jidx) v[j] = fmaf(ag, GMAX - v[j], v[j]);            \
        }                                                                     \
        unsigned snap = ((unsigned)__builtin_amdgcn_readfirstlane((int)meta)  \
                         >> 16) & 0xFu;                                       \
        if (snap) {                                                           \
            int r = (int)snap - 1;                                            \
            float4 o;                                                         \
            o.x = fmaxf(fmaxf(v[0], v[1]), fmaxf(v[8],  v[9]));               \
            o.y = fmaxf(fmaxf(v[2], v[3]), fmaxf(v[10], v[11]));              \
            o.z = fmaxf(fmaxf(v[4], v[5]), fmaxf(v[12], v[13]));              \
            o.w = fmaxf(fmaxf(v[6], v[7]), fmaxf(v[14], v[15]));              \
            float* dst = out +                                                \
                (size_t)((((s * 8 + r) * 2 + p) * 64 + X) * 64 + yc * 4);     \
            *reinterpret_cast<float4*>(dst) = o;                              \
        }                                                                     \
    }

    // ---- main sequential loop, unroll x2, prefetch 2 steps ahead ----
    uint4 c0 = sched[1];
    uint4 c1 = sched[2];
    for (int n = 1; n < SPK; n += 2) {
        uint4 p0 = sched[n + 2];
        uint4 p1 = sched[n + 3];
        STEP(c0);
        STEP(c1);
        c0 = p0;
        c1 = p1;
    }
#undef STEP

    // ---- slots never written at n>=1: default snapshots ----
    for (int r = 0; r < 8; ++r) {
        if (nlast[r] < 0) {
            float4 o = make_float4(0.f, 0.f, 0.f, 0.f);
            if (r == 0 && own0) {                // slot 0 keeps the init point
                float val = PFRAC * (GMAX - GMIN);
                int k0 = (j0 & 7) >> 1;
                if      (k0 == 0) o.x = val;
                else if (k0 == 1) o.y = val;
                else if (k0 == 2) o.z = val;
                else              o.w = val;
            }
            float* dst = out + (size_t)((((s * 8 + r) * 2 + p) * 64 + X) * 64 + yc * 4);
            *reinterpret_cast<float4*>(dst) = o;
        }
    }
}

extern "C" void kernel_launch(void* const* d_in, const int* in_sizes, int n_in,
                              void* d_out, int out_size, void* d_ws, size_t ws_size,
                              hipStream_t stream) {
    const int*   event  = (const int*)  d_in[0];
    const float* ts     = (const float*)d_in[1];
    const int*   tt     = (const int*)  d_in[2];
    const int*   length = (const int*)  d_in[3];
    float*       out    = (float*)d_out;

    trace_kernel<<<dim3(SN * 2 * 4), dim3(256), 0, stream>>>(event, ts, tt, length, out);
}

// Round 4
// 44.350 us; speedup vs baseline: 2.4648x; 1.9317x over previous
//
#include <hip/hip_runtime.h>

#define SN 128
#define SPK 512

constexpr float GMIN  = 0.1f;
constexpr float PFRAC = 0.3f;
constexpr float GMAX  = 1.0f;

// Lazy-decay formulation.
// State per cell: a = (v - GMIN) / C(n_touch), where C(n) = exp((ts0 - ts[n])/TAU)
// => v(n) = C(n)*a + GMIN with zero per-step work.
// Spike touch at step n: v' = v + PFRAC*(GMAX - v)
//   => a' = (1-PFRAC)*a + PFRAC*(GMAX-GMIN)/C(n)  (gated steps excluded in meta).
// sCr[n] pre-stores PFRAC*(GMAX-GMIN)/C(n).
//
// meta word per step n:
//   bits 3-14 : owner pattern (pos & 0x7F78: p<<14 | x<<7 | y, x-LSB/y-low3 stripped)
//   bit 15    : no-match flag (n==0, or gated n>=len)
//   bits 16-19: jidx = (x&1)<<3 | (y&7)
//   bits 20-22: tt value
//   bits 24-26: snapshot slot r   bit 31: snapshot flag (last occurrence of r)
// Owner test: (w & 0xFF78) == mypat.  Snapshot test: (int)w < 0.

__global__ __launch_bounds__(256, 4) void trace_kernel(
    const int*   __restrict__ event,   // (SN, SPK, 3) int32: x, y, pol
    const float* __restrict__ ts,      // (SN, SPK) f32, ascending
    const int*   __restrict__ tt,      // (SN, SPK) int32 in [0,8)
    const int*   __restrict__ length,  // (SN,) int32
    float*       __restrict__ out)     // (SN, 8, 2, 64, 64) f32
{
    __shared__ uint4 smeta4[SPK / 4 + 1];
    __shared__ float sC [SPK];
    __shared__ float sCr[SPK];
    __shared__ int   snlast[8];
    unsigned* smeta = (unsigned*)smeta4;

    const int wg = blockIdx.x;
    const int s  = wg >> 3;
    const int p  = (wg >> 2) & 1;
    const int xc = wg & 3;
    const int t  = threadIdx.x;

    const int   len = length[s];
    const float ts0 = ts[s * SPK];

    if (t < 8) snlast[t] = -1;
    if (t < 4) smeta[SPK + t] = 0x8000u;   // prefetch pad: no-match, no snap
    __syncthreads();

    // ---- build schedule ----
    for (int n = t; n < SPK; n += 256) {
        int   tv  = tt[s * SPK + n];
        float tsn = ts[s * SPK + n];
        sC [n] = expf((ts0 - tsn) * 0.01f);                            // C(n)
        sCr[n] = (PFRAC * (GMAX - GMIN)) * expf((tsn - ts0) * 0.01f);  // P*(GMAX-GMIN)/C(n)
        unsigned w = (unsigned)tv << 20;
        if (n >= 1 && n < len) {
            const int* ev = event + (size_t)(s * SPK + n) * 3;
            int ex = ev[0], ey = ev[1], ep = ev[2];
            unsigned pos = (unsigned)((ep << 14) | (ex << 7) | ey);
            w |= (pos & 0x7F78u) | ((unsigned)(((ex & 1) << 3) | (ey & 7)) << 16);
        } else {
            w |= 0x8000u;
        }
        smeta[n] = w;
        if (n >= 1) atomicMax(&snlast[tv], n);
    }
    __syncthreads();
    // mark last occurrence of each slot (the surviving snapshot)
    for (int n = t; n < SPK; n += 256) {
        if (n >= 1) {
            int tv = (int)((smeta[n] >> 20) & 7u);
            if (snlast[tv] == n)
                smeta[n] |= 0x80000000u | ((unsigned)tv << 24);
        }
    }
    __syncthreads();

    const int Xl     = t >> 4;
    const int yc     = t & 15;
    const int x_even = xc * 32 + 2 * Xl;
    const unsigned mypat = (unsigned)((p << 14) | (x_even << 7) | (yc << 3));
    const int X = xc * 16 + Xl;

    // a[j]: j = (x&1)<<3 | (y&7);  v = C*a + GMIN
    float a[16];
#pragma unroll
    for (int j = 0; j < 16; ++j) a[j] = -GMIN;     // v=0 everywhere initially

    // init spike at n=0 (C(0)=1): a = 0.27 - 0.1 at the init cell
    bool own0 = false; int j0 = 0;
    {
        const int* ev0 = event + (size_t)s * SPK * 3;
        int x0 = ev0[0], y0 = ev0[1], p0 = ev0[2];
        unsigned pos0 = (unsigned)((p0 << 14) | (x0 << 7) | y0);
        if ((pos0 & 0x7F78u) == mypat) {
            own0 = true;
            j0 = ((x0 & 1) << 3) | (y0 & 7);
#pragma unroll
            for (int j = 0; j < 16; ++j)
                if (j == j0) a[j] = PFRAC * (GMAX - GMIN) - GMIN;
        }
    }

    auto step = [&](unsigned mw, int nn) {
        if (__builtin_expect((mw & 0xFF78u) == mypat, 0)) {
            float addb = sCr[nn];
            int jidx = (int)((mw >> 16) & 15u);
#pragma unroll
            for (int j = 0; j < 16; ++j)
                a[j] = (j == jidx) ? fmaf(1.0f - PFRAC, a[j], addb) : a[j];
        }
        if (__builtin_expect((int)mw < 0, 0)) {
            int r = (int)((mw >> 24) & 7u);
            float C = sC[nn];
            float v[16];
#pragma unroll
            for (int j = 0; j < 16; ++j) v[j] = fmaf(C, a[j], GMIN);
            float4 o;
            o.x = fmaxf(fmaxf(v[0], v[1]), fmaxf(v[8],  v[9]));
            o.y = fmaxf(fmaxf(v[2], v[3]), fmaxf(v[10], v[11]));
            o.z = fmaxf(fmaxf(v[4], v[5]), fmaxf(v[12], v[13]));
            o.w = fmaxf(fmaxf(v[6], v[7]), fmaxf(v[14], v[15]));
            float* dst = out +
                (size_t)((((s * 8 + r) * 2 + p) * 64 + X) * 64 + yc * 4);
            *reinterpret_cast<float4*>(dst) = o;
        }
    };

    // ---- main loop: chunked meta scan, 1-chunk prefetch ----
    uint4 cur = smeta4[0];
    for (int c = 0; c < SPK / 4; ++c) {
        uint4 nxt = smeta4[c + 1];
        int n = c * 4;
        step(cur.x, n);
        step(cur.y, n + 1);
        step(cur.z, n + 2);
        step(cur.w, n + 3);
        cur = nxt;
    }

    // ---- slots that never occur at n>=1: default snapshots ----
#pragma unroll
    for (int r = 0; r < 8; ++r) {
        if (snlast[r] < 0) {
            float4 o = make_float4(0.f, 0.f, 0.f, 0.f);
            if (r == 0 && own0) {                  // slot 0 keeps the init point
                float val = PFRAC * (GMAX - GMIN);
                int k0 = (j0 & 7) >> 1;
                if      (k0 == 0) o.x = val;
                else if (k0 == 1) o.y = val;
                else if (k0 == 2) o.z = val;
                else              o.w = val;
            }
            float* dst = out + (size_t)((((s * 8 + r) * 2 + p) * 64 + X) * 64 + yc * 4);
            *reinterpret_cast<float4*>(dst) = o;
        }
    }
}

extern "C" void kernel_launch(void* const* d_in, const int* in_sizes, int n_in,
                              void* d_out, int out_size, void* d_ws, size_t ws_size,
                              hipStream_t stream) {
    const int*   event  = (const int*)  d_in[0];
    const float* ts     = (const float*)d_in[1];
    const int*   tt     = (const int*)  d_in[2];
    const int*   length = (const int*)  d_in[3];
    float*       out    = (float*)d_out;

    trace_kernel<<<dim3(SN * 2 * 4), dim3(256), 0, stream>>>(event, ts, tt, length, out);
}

// Round 5
// 26.220 us; speedup vs baseline: 4.1691x; 1.6915x over previous
//
#include <hip/hip_runtime.h>

#define SN 128
#define SPK 512

constexpr float GMIN  = 0.1f;
constexpr float PFRAC = 0.3f;
constexpr float GMAX  = 1.0f;

// Lazy-decay + compacted per-block event list.
// State per cell: a = (v - GMIN) / C(n), C(n) = exp((ts0 - ts[n])/TAU)
//   => v(n) = C(n)*a + GMIN, zero per-step work.
// Spike touch at step n: a' = (1-PFRAC)*a + PFRAC*(GMAX-GMIN)/C(n).
// Only steps that touch THIS block (owner events, gated by length) or that are
// the surviving snapshot of a slot matter -> compact those (stable order) and
// iterate only the survivors (~40 of 511).
//
// Compact entry (uint4): .x = meta, .y = bits(C), .z = bits(0.27/C), .w unused
// meta: bits 3-6 y>>3 | bits 8-13 x>>1 | bit 14 p | bit 15 owner-valid |
//       bits 16-19 jidx ((x&1)<<3 | (y&7)) | bits 24-26 snap slot | bit 31 snap flag

__global__ __launch_bounds__(256, 4) void trace_kernel(
    const int*   __restrict__ event,   // (SN, SPK, 3) int32: x, y, pol
    const float* __restrict__ ts,      // (SN, SPK) f32, ascending
    const int*   __restrict__ tt,      // (SN, SPK) int32 in [0,8)
    const int*   __restrict__ length,  // (SN,) int32
    float*       __restrict__ out)     // (SN, 8, 2, 64, 64) f32
{
    __shared__ uint4 scomp[SPK + 1];
    __shared__ int   snlast[8];
    __shared__ int   wtot[4];

    const int wg = blockIdx.x;
    const int s  = wg >> 3;
    const int p  = (wg >> 2) & 1;
    const int xc = wg & 3;
    const int t  = threadIdx.x;

    const int   len = length[s];
    const float ts0 = ts[s * SPK];

    if (t < 8) snlast[t] = -1;
    __syncthreads();

    // ---- pass A: last occurrence of each slot value ----
    for (int n = t; n < SPK; n += 256) {
        if (n >= 1) atomicMax(&snlast[tt[s * SPK + n]], n);
    }
    __syncthreads();

    // ---- pass B: stable compaction of relevant steps (2 rounds of 256) ----
    const int lane = t & 63;
    const int wid  = t >> 6;
    const unsigned long long lmask = (1ull << lane) - 1ull;

    int base = 0;
    for (int r = 0; r < 2; ++r) {
        int n = r * 256 + t;
        int   tv  = tt[s * SPK + n];
        float tsn = ts[s * SPK + n];

        bool powner = false, psnap = false;
        int ex = 0, ey = 0;
        if (n >= 1) {
            psnap = (snlast[tv] == n);
            if (n < len) {
                const int* ev = event + (size_t)(s * SPK + n) * 3;
                ex = ev[0]; ey = ev[1];
                int ep = ev[2];
                powner = (ep == p) && ((ex >> 5) == xc);
            }
        }
        bool pred = powner || psnap;

        unsigned long long mask = __ballot(pred);
        int my = __popcll(mask & lmask);
        if (lane == 0) wtot[wid] = __popcll(mask);
        __syncthreads();
        int pre = base + my;
        for (int w = 0; w < 4; ++w) {
            int c = wtot[w];
            if (w < wid) pre += c;
        }
        if (pred) {
            float C  = expf((ts0 - tsn) * 0.01f);          // TAU = 100
            float Cr = (PFRAC * (GMAX - GMIN)) / C;
            unsigned mw = 0u;
            if (powner) {
                unsigned pos = (unsigned)((p << 14) | (ex << 7) | ey);
                mw |= 0x8000u | (pos & 0x7F78u)
                    | ((unsigned)(((ex & 1) << 3) | (ey & 7)) << 16);
            }
            if (psnap) mw |= 0x80000000u | ((unsigned)tv << 24);
            scomp[pre] = make_uint4(mw, __float_as_uint(C), __float_as_uint(Cr), 0u);
        }
        base += wtot[0] + wtot[1] + wtot[2] + wtot[3];
        __syncthreads();
    }
    const int cnt = base;
    if (t == 0) scomp[cnt] = make_uint4(0u, 0u, 0u, 0u);   // prefetch pad
    __syncthreads();

    // ---- per-thread cell block ----
    const int Xl     = t >> 4;
    const int yc     = t & 15;
    const int x_even = xc * 32 + 2 * Xl;
    const unsigned mypatO = (unsigned)((p << 14) | (x_even << 7) | (yc << 3)) | 0x8000u;
    const int X = xc * 16 + Xl;

    float a[16];
#pragma unroll
    for (int j = 0; j < 16; ++j) a[j] = -GMIN;             // v = 0 everywhere

    // init spike at n=0 (C(0)=1)
    bool own0 = false; int j0 = 0;
    {
        const int* ev0 = event + (size_t)s * SPK * 3;
        int x0 = ev0[0], y0 = ev0[1], p0 = ev0[2];
        unsigned pos0 = (unsigned)((p0 << 14) | (x0 << 7) | y0);
        if ((pos0 & 0x7F78u) == (mypatO & 0x7F78u)) {
            own0 = true;
            j0 = ((x0 & 1) << 3) | (y0 & 7);
#pragma unroll
            for (int j = 0; j < 16; ++j)
                if (j == j0) a[j] = PFRAC * (GMAX - GMIN) - GMIN;
        }
    }

    // ---- compacted main loop ----
    uint4 cur = scomp[0];
    for (int i = 0; i < cnt; ++i) {
        uint4 nxt = scomp[i + 1];
        unsigned mw = cur.x;
        if (__builtin_expect((mw & 0xFF78u) == mypatO, 0)) {
            float addb = __uint_as_float(cur.z);
            int jidx = (int)((mw >> 16) & 15u);
#pragma unroll
            for (int j = 0; j < 16; ++j)
                a[j] = (j == jidx) ? fmaf(1.0f - PFRAC, a[j], addb) : a[j];
        }
        if (__builtin_expect((int)mw < 0, 0)) {
            int rr = (int)((mw >> 24) & 7u);
            float C = __uint_as_float(cur.y);
            float v[16];
#pragma unroll
            for (int j = 0; j < 16; ++j) v[j] = fmaf(C, a[j], GMIN);
            float4 o;
            o.x = fmaxf(fmaxf(v[0], v[1]), fmaxf(v[8],  v[9]));
            o.y = fmaxf(fmaxf(v[2], v[3]), fmaxf(v[10], v[11]));
            o.z = fmaxf(fmaxf(v[4], v[5]), fmaxf(v[12], v[13]));
            o.w = fmaxf(fmaxf(v[6], v[7]), fmaxf(v[14], v[15]));
            float* dst = out +
                (size_t)((((s * 8 + rr) * 2 + p) * 64 + X) * 64 + yc * 4);
            *reinterpret_cast<float4*>(dst) = o;
        }
        cur = nxt;
    }

    // ---- slots that never occur at n>=1: default snapshots ----
#pragma unroll
    for (int r = 0; r < 8; ++r) {
        if (snlast[r] < 0) {
            float4 o = make_float4(0.f, 0.f, 0.f, 0.f);
            if (r == 0 && own0) {                          // slot 0 keeps init point
                float val = PFRAC * (GMAX - GMIN);
                int k0 = (j0 & 7) >> 1;
                if      (k0 == 0) o.x = val;
                else if (k0 == 1) o.y = val;
                else if (k0 == 2) o.z = val;
                else              o.w = val;
            }
            float* dst = out + (size_t)((((s * 8 + r) * 2 + p) * 64 + X) * 64 + yc * 4);
            *reinterpret_cast<float4*>(dst) = o;
        }
    }
}

extern "C" void kernel_launch(void* const* d_in, const int* in_sizes, int n_in,
                              void* d_out, int out_size, void* d_ws, size_t ws_size,
                              hipStream_t stream) {
    const int*   event  = (const int*)  d_in[0];
    const float* ts     = (const float*)d_in[1];
    const int*   tt     = (const int*)  d_in[2];
    const int*   length = (const int*)  d_in[3];
    float*       out    = (float*)d_out;

    trace_kernel<<<dim3(SN * 2 * 4), dim3(256), 0, stream>>>(event, ts, tt, length, out);
}